// Round 8
// baseline (258.558 us; speedup 1.0000x reference)
//
#include <hip/hip_runtime.h>

// Discounted cumulative return y[t] = r[t] + a[t]*y[t+1], a[t]=terminal[t]?0:0.99
// Round 15: WAVE-AUTONOMOUS k_local. Every prior variant phase-locked all
// resident waves with block barriers (load phase, then store phase, chip-wide),
// which matches the measured 62.5us == 128MB/3.15 + 64MB/3.15 (serialized
// directions). Copy kernels (6.29 TB/s combined) have no barriers and overlap
// R/W. This round: segment = 4096 elems PER WAVE (64/lane), scan closed
// entirely with shfl — no LDS, no __syncthreads. Waves free-run like copy.
// k_fix adapted: 4096 segment aggs, 2 segments per fix-block.
//
//   K1: per-wave segment-local scan (y_in=0) -> out; agg[s]=(A,B), lastT[s].
//   K2: per-segment y_in by composing aggs of higher segments; correction
//       out[i] += 0.99^(segHi+1-i) * y_in past the segment's last terminal.
//
// Affine F(x)=A*x+B maps y[hi+1]->y[lo]; compose outer = lower indices:
// (A1,B1)o(A2,B2) = (A1*A2, A1*B2+B1).

constexpr int   SEG    = 4096;            // elems per wave-segment
constexpr int   IPL    = SEG / 64;        // 64 elems per lane
constexpr int   TPB    = 256;             // 4 independent waves per block
constexpr int   WPB    = TPB / 64;
constexpr int   FTPB   = 256;             // k_fix block size
constexpr float DISC   = 0.99f;
constexpr float L2DISC = -0.0144995696f;  // log2(0.99)

// Inclusive wave SUFFIX scan: lane l ends with F_l o F_{l+1} o ... o F_63.
__device__ __forceinline__ void wave_suffix_scan(float& A, float& B, int lane) {
    #pragma unroll
    for (int off = 1; off < 64; off <<= 1) {
        float oA = __shfl_down(A, off, 64);
        float oB = __shfl_down(B, off, 64);
        if (lane + off < 64) { B = A * oB + B; A = A * oA; }
    }
}

// K1: segment-local scan (y_in = 0) -> out; write agg[s] and lastT[s].
// NO LDS, NO BARRIERS — each wave is fully autonomous.
__global__ __launch_bounds__(TPB) void k_local(
        const int* __restrict__ term, const float* __restrict__ rew,
        float* __restrict__ out, float2* __restrict__ agg,
        int* __restrict__ lastT, int nSeg, long long T) {
    const int lane = threadIdx.x & 63;
    const int wav  = threadIdx.x >> 6;
    const int seg  = blockIdx.x * WPB + wav;
    if (seg >= nSeg) return;

    const long long segLo = (long long)seg * SEG;
    const long long base  = segLo + (long long)lane * IPL;
    const bool fast = (segLo + SEG <= T);

    float r[IPL];
    unsigned long long mask = 0;

    if (fast) {
        const float4* rp = (const float4*)(rew + base);
        const int4*   tp = (const int4*)(term + base);
        #pragma unroll
        for (int q = 0; q < IPL / 4; ++q) {
            float4 rv = rp[q];
            int4   tv = tp[q];
            r[4*q+0] = rv.x; r[4*q+1] = rv.y; r[4*q+2] = rv.z; r[4*q+3] = rv.w;
            unsigned mb = (tv.x ? 1u : 0u) | (tv.y ? 2u : 0u)
                        | (tv.z ? 4u : 0u) | (tv.w ? 8u : 0u);
            mask |= (unsigned long long)mb << (4*q);
        }
    } else {
        #pragma unroll 4
        for (int k = 0; k < IPL; ++k) {
            long long i = base + k;
            if (i < T) { r[k] = rew[i]; if (term[i]) mask |= 1ull << k; }
            else       { r[k] = 0.f; }
        }
    }

    // lane-local compose, high->low
    float A = 1.f, B = 0.f;
    if (fast) {
        #pragma unroll
        for (int k = IPL - 1; k >= 0; --k) {
            float ak = ((mask >> k) & 1ull) ? 0.f : DISC;
            B = ak * B + r[k]; A = ak * A;
        }
    } else {
        #pragma unroll 4
        for (int k = IPL - 1; k >= 0; --k) {
            float ak = ((mask >> k) & 1ull) ? 0.f : DISC;
            if (base + k >= T) ak = 1.f;
            B = ak * B + r[k]; A = ak * A;
        }
    }

    float IA = A, IB = B;
    wave_suffix_scan(IA, IB, lane);     // lane 0 ends with whole-wave compose

    long long myLast = mask ? (base + (63 - __clzll(mask))) : -1;
    #pragma unroll
    for (int off = 32; off > 0; off >>= 1) {
        long long o = __shfl_down(myLast, off, 64);
        myLast = max(myLast, o);
    }

    float EA = __shfl_down(IA, 1, 64);
    float EB = __shfl_down(IB, 1, 64);
    if (lane == 63) { EA = 1.f; EB = 0.f; }
    (void)EA;

    float y = EB;                       // y entering this lane's span (seg y_in = 0)
    if (fast) {
        #pragma unroll
        for (int k = IPL - 1; k >= 0; --k) {
            float ak = ((mask >> k) & 1ull) ? 0.f : DISC;
            y = ak * y + r[k]; r[k] = y;
        }
        float4* op = (float4*)(out + base);
        #pragma unroll
        for (int q = 0; q < IPL / 4; ++q)
            op[q] = make_float4(r[4*q+0], r[4*q+1], r[4*q+2], r[4*q+3]);
    } else {
        #pragma unroll 4
        for (int k = IPL - 1; k >= 0; --k) {
            float ak = ((mask >> k) & 1ull) ? 0.f : DISC;
            if (base + k >= T) ak = 1.f;
            y = ak * y + r[k]; r[k] = y;
        }
        for (int k = 0; k < IPL; ++k) {
            long long i = base + k;
            if (i < T) out[i] = r[k];
        }
    }

    if (lane == 0) {
        agg[seg]   = make_float2(IA, IB);
        lastT[seg] = (int)max(myLast, segLo - 1);   // segLo-1 == "no terminal"
    }
}

// K2: per-segment y_in from aggregates above, then sparse tail corrections.
// Block b handles segments s1 = 2b+1 (higher) and s0 = 2b.
__global__ __launch_bounds__(FTPB) void k_fix(
        const float2* __restrict__ agg, const int* __restrict__ lastT,
        float* __restrict__ out, int nSeg, long long T) {
    __shared__ float2 sWB[FTPB / 64];

    const int t = threadIdx.x;
    const int lane = t & 63, wav = t >> 6;
    const int b = blockIdx.x;
    const int s0 = 2 * b;
    const int s1 = 2 * b + 1;

    // compose aggregates of all segments g > s1 (outer = lower g)
    const int cpt = (nSeg + FTPB - 1) / FTPB;        // 16 for 4096
    float VA = 1.f, VB = 0.f;
    #pragma unroll
    for (int k = cpt - 1; k >= 0; --k) {             // descending g: inner first
        int g = t * cpt + k;
        if (g > s1 && g < nSeg) {
            float2 q = agg[g];
            VB = q.x * VB + q.y; VA = q.x * VA;
        }
    }
    wave_suffix_scan(VA, VB, lane);
    if (lane == 0) sWB[wav] = make_float2(VA, VB);
    __syncthreads();

    float FA = sWB[0].x, FB = sWB[0].y;              // wave 0 outermost
    #pragma unroll
    for (int w = 1; w < FTPB / 64; ++w) {
        float2 h = sWB[w];
        FB = FA * h.y + FB; FA = FA * h.x;
    }

    const float yin1 = FB;                           // y entering segment s1
    float yin0;                                      // y entering segment s0
    if (s1 < nSeg) {
        float2 a1 = agg[s1];
        yin0 = a1.x * yin1 + a1.y;
    } else {
        yin0 = yin1;        // no segment s1: compose over g>s1 == over g>s0
    }

    // correction for segment s1
    if (s1 < nSeg && yin1 != 0.f) {
        const long long sLo = (long long)s1 * SEG;
        const long long sHi = min(sLo + (long long)SEG, T) - 1;
        const long long start = (long long)lastT[s1] + 1;
        for (long long i = start + t; i <= sHi; i += FTPB) {
            float d = (float)(int)(sHi + 1 - i);
            out[i] += exp2f(d * L2DISC) * yin1;
        }
    }
    // correction for segment s0
    if (s0 < nSeg && yin0 != 0.f) {
        const long long sLo = (long long)s0 * SEG;
        const long long sHi = min(sLo + (long long)SEG, T) - 1;
        const long long start = (long long)lastT[s0] + 1;
        for (long long i = start + t; i <= sHi; i += FTPB) {
            float d = (float)(int)(sHi + 1 - i);
            out[i] += exp2f(d * L2DISC) * yin0;
        }
    }
}

extern "C" void kernel_launch(void* const* d_in, const int* in_sizes, int n_in,
                              void* d_out, int out_size, void* d_ws, size_t ws_size,
                              hipStream_t stream) {
    const int*   term = (const int*)d_in[0];
    const float* rew  = (const float*)d_in[1];
    float*       out  = (float*)d_out;

    const long long T = (long long)in_sizes[1];
    const int nSeg = (int)((T + SEG - 1) / SEG);          // 4096 for T=2^24

    float2* agg   = (float2*)d_ws;
    int*    lastT = (int*)(agg + nSeg);

    const int blocksLocal = (nSeg + WPB - 1) / WPB;       // 1024
    const int blocksFix   = (nSeg + 1) / 2;               // 2048

    k_local<<<blocksLocal, TPB, 0, stream>>>(term, rew, out, agg, lastT, nSeg, T);
    k_fix  <<<blocksFix,   FTPB, 0, stream>>>(agg, lastT, out, nSeg, T);
}

// Round 9
// 190.104 us; speedup vs baseline: 1.3601x; 1.3601x over previous
//
#include <hip/hip_runtime.h>

// Discounted cumulative return y[t] = r[t] + a[t]*y[t+1], a[t]=terminal[t]?0:0.99
// Round 16: wave-autonomous k_local (no LDS, no __syncthreads) with R12's
// PROVEN layout (thread owns 8 contiguous elems, lane-stride 32B -> exact
// FETCH/WRITE, no amplification). R15's 256B-lane-stride was a layout
// confound (FETCH 228MB, WRITE 193MB). Per-wave segment = 4096 elems as 8
// chained chunks of 512; chunks chain via broadcast scalar only, so each wave
// free-runs and interleaves loads of chunk c-1 with stores of chunk c —
// copy-style R/W overlap, which the barrier-phase-locked variants never had.
// k_fix = R15's verified version unchanged (nSeg=4096, 2 segments/block).
//
// Affine F(x)=A*x+B maps y[hi+1]->y[lo]; compose outer = lower indices:
// (A1,B1)o(A2,B2) = (A1*A2, A1*B2+B1).

constexpr int   SEG    = 4096;            // elems per wave-segment
constexpr int   CHUNK  = 512;             // elems per wave-chunk (64 lanes x 8)
constexpr int   NCH    = SEG / CHUNK;     // 8 chained chunks
constexpr int   IPT    = 8;               // elems per lane per chunk
constexpr int   TPB    = 256;             // 4 independent waves per block
constexpr int   WPB    = TPB / 64;
constexpr int   FTPB   = 256;             // k_fix block size
constexpr float DISC   = 0.99f;
constexpr float L2DISC = -0.0144995696f;  // log2(0.99)

// Inclusive wave SUFFIX scan: lane l ends with F_l o F_{l+1} o ... o F_63.
__device__ __forceinline__ void wave_suffix_scan(float& A, float& B, int lane) {
    #pragma unroll
    for (int off = 1; off < 64; off <<= 1) {
        float oA = __shfl_down(A, off, 64);
        float oB = __shfl_down(B, off, 64);
        if (lane + off < 64) { B = A * oB + B; A = A * oA; }
    }
}

// K1: per-wave segment scan (y_in = 0) -> out; write agg[s] and lastT[s].
// NO LDS, NO BARRIERS — each wave fully autonomous, chunks chained in-wave.
__global__ __launch_bounds__(TPB) void k_local(
        const int* __restrict__ term, const float* __restrict__ rew,
        float* __restrict__ out, float2* __restrict__ agg,
        int* __restrict__ lastT, int nSeg, long long T) {
    const int lane = threadIdx.x & 63;
    const int wav  = threadIdx.x >> 6;
    const int seg  = blockIdx.x * WPB + wav;
    if (seg >= nSeg) return;

    const long long segLo = (long long)seg * SEG;
    const bool fast = (segLo + SEG <= T);

    float At = 1.f, Bt = 0.f;   // segment aggregate over processed (higher) chunks
    int   ltLane = -1;          // per-lane running last-terminal (global idx, int ok: T=2^24)

    if (fast) {
        float4 bR[2][IPT / 4];
        int4   bT[2][IPT / 4];

        // prefetch highest chunk
        {
            const long long base = segLo + (long long)(NCH - 1) * CHUNK
                                        + (long long)lane * IPT;
            const float4* rp = (const float4*)(rew + base);
            const int4*   tp = (const int4*)(term + base);
            #pragma unroll
            for (int q = 0; q < IPT / 4; ++q) {
                bR[(NCH - 1) & 1][q] = rp[q];
                bT[(NCH - 1) & 1][q] = tp[q];
            }
        }

        #pragma unroll
        for (int c = NCH - 1; c >= 0; --c) {
            // issue next (lower) chunk's loads before computing this one
            if (c > 0) {
                const long long nbase = segLo + (long long)(c - 1) * CHUNK
                                             + (long long)lane * IPT;
                const float4* rp = (const float4*)(rew + nbase);
                const int4*   tp = (const int4*)(term + nbase);
                #pragma unroll
                for (int q = 0; q < IPT / 4; ++q) {
                    bR[(c - 1) & 1][q] = rp[q];
                    bT[(c - 1) & 1][q] = tp[q];
                }
            }
            const int p = c & 1;
            const long long base = segLo + (long long)c * CHUNK + (long long)lane * IPT;

            float r[IPT];
            unsigned mask = 0;
            #pragma unroll
            for (int q = 0; q < IPT / 4; ++q) {
                float4 rv = bR[p][q];
                int4   tv = bT[p][q];
                r[4*q+0] = rv.x; r[4*q+1] = rv.y; r[4*q+2] = rv.z; r[4*q+3] = rv.w;
                mask |= (tv.x ? 1u : 0u) << (4*q+0);
                mask |= (tv.y ? 1u : 0u) << (4*q+1);
                mask |= (tv.z ? 1u : 0u) << (4*q+2);
                mask |= (tv.w ? 1u : 0u) << (4*q+3);
            }

            // lane-local compose, high->low
            float A = 1.f, B = 0.f;
            #pragma unroll
            for (int k = IPT - 1; k >= 0; --k) {
                float ak = ((mask >> k) & 1u) ? 0.f : DISC;
                B = ak * B + r[k]; A = ak * A;
            }

            float IA = A, IB = B;
            wave_suffix_scan(IA, IB, lane);

            if (mask) ltLane = max(ltLane, (int)(base + (31 - __clz(mask))));

            // chunk aggregate = lane 0's inclusive scan, broadcast
            const float GA = __shfl(IA, 0, 64);
            const float GB = __shfl(IB, 0, 64);

            // exclusive suffix for this lane (lanes lane+1..63)
            float EA = __shfl_down(IA, 1, 64);
            float EB = __shfl_down(IB, 1, 64);
            if (lane == 63) { EA = 1.f; EB = 0.f; }

            // y entering this lane's span; y entering chunk from above = Bt
            float y = EA * Bt + EB;

            #pragma unroll
            for (int k = IPT - 1; k >= 0; --k) {
                float ak = ((mask >> k) & 1u) ? 0.f : DISC;
                y = ak * y + r[k]; r[k] = y;
            }

            float4* op = (float4*)(out + base);
            #pragma unroll
            for (int q = 0; q < IPT / 4; ++q)
                op[q] = make_float4(r[4*q+0], r[4*q+1], r[4*q+2], r[4*q+3]);

            // fold chunk into segment aggregate: F_new = F_chunk o F_prev
            Bt = GA * Bt + GB;
            At = GA * At;
        }
    } else {
        // guarded tail segment (only when T % SEG != 0)
        for (int c = NCH - 1; c >= 0; --c) {
            const long long base = segLo + (long long)c * CHUNK + (long long)lane * IPT;
            float r[IPT];
            unsigned mask = 0;
            #pragma unroll
            for (int k = 0; k < IPT; ++k) {
                long long i = base + k;
                if (i < T) { r[k] = rew[i]; mask |= (term[i] ? 1u : 0u) << k; }
                else       { r[k] = 0.f; }
            }
            float A = 1.f, B = 0.f;
            #pragma unroll
            for (int k = IPT - 1; k >= 0; --k) {
                float ak = ((mask >> k) & 1u) ? 0.f : DISC;
                if (base + k >= T) ak = 1.f;
                B = ak * B + r[k]; A = ak * A;
            }
            float IA = A, IB = B;
            wave_suffix_scan(IA, IB, lane);

            if (mask) ltLane = max(ltLane, (int)(base + (31 - __clz(mask))));

            const float GA = __shfl(IA, 0, 64);
            const float GB = __shfl(IB, 0, 64);

            float EA = __shfl_down(IA, 1, 64);
            float EB = __shfl_down(IB, 1, 64);
            if (lane == 63) { EA = 1.f; EB = 0.f; }

            float y = EA * Bt + EB;

            #pragma unroll
            for (int k = IPT - 1; k >= 0; --k) {
                float ak = ((mask >> k) & 1u) ? 0.f : DISC;
                if (base + k >= T) ak = 1.f;
                y = ak * y + r[k]; r[k] = y;
            }
            #pragma unroll
            for (int k = 0; k < IPT; ++k) {
                long long i = base + k;
                if (i < T) out[i] = r[k];
            }

            Bt = GA * Bt + GB;
            At = GA * At;
        }
    }

    // single wave-reduce of last-terminal at the end
    int lt = ltLane;
    #pragma unroll
    for (int off = 32; off > 0; off >>= 1)
        lt = max(lt, __shfl_down(lt, off, 64));

    if (lane == 0) {
        agg[seg]   = make_float2(At, Bt);
        lastT[seg] = max(lt, (int)segLo - 1);   // segLo-1 == "no terminal"
    }
}

// K2: per-segment y_in from aggregates above, then sparse tail corrections.
// Block b handles segments s1 = 2b+1 (higher) and s0 = 2b. (R15-verified.)
__global__ __launch_bounds__(FTPB) void k_fix(
        const float2* __restrict__ agg, const int* __restrict__ lastT,
        float* __restrict__ out, int nSeg, long long T) {
    __shared__ float2 sWB[FTPB / 64];

    const int t = threadIdx.x;
    const int lane = t & 63, wav = t >> 6;
    const int b = blockIdx.x;
    const int s0 = 2 * b;
    const int s1 = 2 * b + 1;

    // compose aggregates of all segments g > s1 (outer = lower g)
    const int cpt = (nSeg + FTPB - 1) / FTPB;        // 16 for 4096
    float VA = 1.f, VB = 0.f;
    #pragma unroll
    for (int k = cpt - 1; k >= 0; --k) {             // descending g: inner first
        int g = t * cpt + k;
        if (g > s1 && g < nSeg) {
            float2 q = agg[g];
            VB = q.x * VB + q.y; VA = q.x * VA;
        }
    }
    wave_suffix_scan(VA, VB, lane);
    if (lane == 0) sWB[wav] = make_float2(VA, VB);
    __syncthreads();

    float FA = sWB[0].x, FB = sWB[0].y;              // wave 0 outermost
    #pragma unroll
    for (int w = 1; w < FTPB / 64; ++w) {
        float2 h = sWB[w];
        FB = FA * h.y + FB; FA = FA * h.x;
    }

    const float yin1 = FB;                           // y entering segment s1
    float yin0;                                      // y entering segment s0
    if (s1 < nSeg) {
        float2 a1 = agg[s1];
        yin0 = a1.x * yin1 + a1.y;
    } else {
        yin0 = yin1;        // no segment s1: compose over g>s1 == over g>s0
    }

    // correction for segment s1
    if (s1 < nSeg && yin1 != 0.f) {
        const long long sLo = (long long)s1 * SEG;
        const long long sHi = min(sLo + (long long)SEG, T) - 1;
        const long long start = (long long)lastT[s1] + 1;
        for (long long i = start + t; i <= sHi; i += FTPB) {
            float d = (float)(int)(sHi + 1 - i);
            out[i] += exp2f(d * L2DISC) * yin1;
        }
    }
    // correction for segment s0
    if (s0 < nSeg && yin0 != 0.f) {
        const long long sLo = (long long)s0 * SEG;
        const long long sHi = min(sLo + (long long)SEG, T) - 1;
        const long long start = (long long)lastT[s0] + 1;
        for (long long i = start + t; i <= sHi; i += FTPB) {
            float d = (float)(int)(sHi + 1 - i);
            out[i] += exp2f(d * L2DISC) * yin0;
        }
    }
}

extern "C" void kernel_launch(void* const* d_in, const int* in_sizes, int n_in,
                              void* d_out, int out_size, void* d_ws, size_t ws_size,
                              hipStream_t stream) {
    const int*   term = (const int*)d_in[0];
    const float* rew  = (const float*)d_in[1];
    float*       out  = (float*)d_out;

    const long long T = (long long)in_sizes[1];
    const int nSeg = (int)((T + SEG - 1) / SEG);          // 4096 for T=2^24

    float2* agg   = (float2*)d_ws;
    int*    lastT = (int*)(agg + nSeg);

    const int blocksLocal = (nSeg + WPB - 1) / WPB;       // 1024
    const int blocksFix   = (nSeg + 1) / 2;               // 2048

    k_local<<<blocksLocal, TPB, 0, stream>>>(term, rew, out, agg, lastT, nSeg, T);
    k_fix  <<<blocksFix,   FTPB, 0, stream>>>(agg, lastT, out, nSeg, T);
}

// Round 10
// 177.564 us; speedup vs baseline: 1.4561x; 1.0706x over previous
//
#include <hip/hip_runtime.h>

// Discounted cumulative return y[t] = r[t] + a[t]*y[t+1], a[t]=terminal[t]?0:0.99
// Round 17: RESTORE R12 — the best harness-verified configuration (175.97us,
// k_local 62.5us). Rounds 9-16 falsified every structural theory for the
// ~3.2 TB/s effective-rate wall (latency depth, occupancy, barriers, lane
// density, NT stores, fusion, R/W phase overlap) with clean byte-exact traffic;
// R15 demonstrated the memory system maxing at ~3.3 TB/s real HBM traffic for
// this op shape. Roofline arithmetic:
//   k_local: 192 MB irreducible (64 rew + 64 term reads, 64 out writes)
//            at ~3.3 TB/s demonstrated ceiling = ~58us floor (measured 62.5)
//   k_fix:   ~15-19us (launch + ~16 MB sparse tail RMW)
//   fixed:   ~95us harness/launch overhead (invariant across all rounds)
//   => dur floor ~170us; R12 measured 176.0 (within 3.5%)
//
//   K1: in-block scan with y_in=0 -> out, per-block aggregate (A,B) + last
//       terminal index. TPB=1024 (16 waves), IPTC=8, TILE=8192, ONE barrier.
//   K2: per-block compose of aggregates above -> y_in; correction
//       out[i] += 0.99^(hi+1-i) * y_in only past the block's last terminal.
//
// Affine F(x)=A*x+B maps y[hi+1]->y[lo]; compose outer = lower indices:
// (A1,B1)o(A2,B2) = (A1*A2, A1*B2+B1).

constexpr int   TPB   = 1024;            // 16 waves
constexpr int   NWAV  = TPB / 64;        // 16
constexpr int   IPTC  = 8;               // elems per thread
constexpr int   TILE  = TPB * IPTC;      // 8192 elems per block
constexpr float DISC  = 0.99f;
constexpr float L2DISC = -0.0144995696f; // log2(0.99)

constexpr int   FTPB  = 256;             // k_fix block size

// Inclusive wave SUFFIX scan: lane l ends with F_l o F_{l+1} o ... o F_63.
__device__ __forceinline__ void wave_suffix_scan(float& A, float& B, int lane) {
    #pragma unroll
    for (int off = 1; off < 64; off <<= 1) {
        float oA = __shfl_down(A, off, 64);
        float oB = __shfl_down(B, off, 64);
        if (lane + off < 64) { B = A * oB + B; A = A * oA; }
    }
}

// K1: local scan (y_in = 0) -> out; write agg[b] and lastT[b].
__global__ __launch_bounds__(TPB) void k_local(
        const int* __restrict__ term, const float* __restrict__ rew,
        float* __restrict__ out, float2* __restrict__ agg,
        int* __restrict__ lastT, long long T) {
    __shared__ float2 sWA[NWAV];
    __shared__ int    sLast[NWAV];

    const int t = threadIdx.x;
    const int lane = t & 63, wav = t >> 6;
    const int b = blockIdx.x;
    const long long lo = (long long)b * TILE;
    const bool fastblk = (lo + TILE <= T);

    float At, Bt;               // block aggregate
    int   lt;                   // last terminal global index in block

    if (fastblk) {
        const long long base = lo + (long long)t * IPTC;

        float4 bR[IPTC / 4];
        int4   bT[IPTC / 4];
        {
            const float4* rp = (const float4*)(rew + base);
            const int4*   tp = (const int4*)(term + base);
            #pragma unroll
            for (int q = 0; q < IPTC / 4; ++q) {
                bR[q] = rp[q];
                bT[q] = tp[q];
            }
        }

        float r[IPTC];
        unsigned mask = 0;
        #pragma unroll
        for (int q = 0; q < IPTC / 4; ++q) {
            float4 rv = bR[q];
            int4   tv = bT[q];
            r[4*q+0] = rv.x; r[4*q+1] = rv.y; r[4*q+2] = rv.z; r[4*q+3] = rv.w;
            mask |= (tv.x ? 1u : 0u) << (4*q+0);
            mask |= (tv.y ? 1u : 0u) << (4*q+1);
            mask |= (tv.z ? 1u : 0u) << (4*q+2);
            mask |= (tv.w ? 1u : 0u) << (4*q+3);
        }

        // thread-local compose, high->low
        float A = 1.f, B = 0.f;
        #pragma unroll
        for (int k = IPTC - 1; k >= 0; --k) {
            float ak = ((mask >> k) & 1u) ? 0.f : DISC;
            B = ak * B + r[k]; A = ak * A;
        }

        float IA = A, IB = B;
        wave_suffix_scan(IA, IB, lane);

        int myLast = mask ? (int)(base + (31 - __clz(mask))) : -1;
        #pragma unroll
        for (int off = 32; off > 0; off >>= 1)
            myLast = max(myLast, __shfl_down(myLast, off, 64));

        if (lane == 0) { sWA[wav] = make_float2(IA, IB); sLast[wav] = myLast; }
        __syncthreads();   // the ONLY barrier in the block

        // block aggregate + per-wave exclusives (all threads, redundant & cheap)
        float2 g = sWA[0];
        int cl = sLast[0];
        #pragma unroll
        for (int w = 1; w < NWAV; ++w) {
            float2 h = sWA[w];
            g.y = g.x * h.y + g.y; g.x = g.x * h.x;
            cl = max(cl, sLast[w]);
        }
        float EWA = 1.f, EWB = 0.f;
        #pragma unroll
        for (int w = 0; w < NWAV; ++w)
            if (w > wav) { float2 h = sWA[w]; EWB = EWA*h.y + EWB; EWA = EWA*h.x; }

        float EA = __shfl_down(IA, 1, 64);
        float EB = __shfl_down(IB, 1, 64);
        if (lane == 63) { EA = 1.f; EB = 0.f; }

        // y entering this thread's span (block-level y_in = 0)
        float y = EA * EWB + EB;

        #pragma unroll
        for (int k = IPTC - 1; k >= 0; --k) {
            float ak = ((mask >> k) & 1u) ? 0.f : DISC;
            y = ak * y + r[k]; r[k] = y;
        }

        float4* op = (float4*)(out + base);
        #pragma unroll
        for (int q = 0; q < IPTC / 4; ++q)
            op[q] = make_float4(r[4*q+0], r[4*q+1], r[4*q+2], r[4*q+3]);

        At = g.x; Bt = g.y; lt = cl;
    } else {
        // guarded tail block (only the last block when T % TILE != 0)
        const long long base = lo + (long long)t * IPTC;
        float r[IPTC];
        unsigned mask = 0;
        #pragma unroll
        for (int k = 0; k < IPTC; ++k) {
            long long i = base + k;
            if (i < T) { r[k] = rew[i]; mask |= (term[i] ? 1u : 0u) << k; }
            else       { r[k] = 0.f; }
        }
        float A = 1.f, B = 0.f;
        #pragma unroll
        for (int k = IPTC - 1; k >= 0; --k) {
            float ak = ((mask >> k) & 1u) ? 0.f : DISC;
            if (base + k >= T) ak = 1.f;
            B = ak * B + r[k]; A = ak * A;
        }
        float IA = A, IB = B;
        wave_suffix_scan(IA, IB, lane);

        int myLast = mask ? (int)(base + (31 - __clz(mask))) : -1;
        #pragma unroll
        for (int off = 32; off > 0; off >>= 1)
            myLast = max(myLast, __shfl_down(myLast, off, 64));

        if (lane == 0) { sWA[wav] = make_float2(IA, IB); sLast[wav] = myLast; }
        __syncthreads();

        float2 g = sWA[0];
        int cl = sLast[0];
        #pragma unroll
        for (int w = 1; w < NWAV; ++w) {
            float2 h = sWA[w];
            g.y = g.x * h.y + g.y; g.x = g.x * h.x;
            cl = max(cl, sLast[w]);
        }
        float EWA = 1.f, EWB = 0.f;
        #pragma unroll
        for (int w = 0; w < NWAV; ++w)
            if (w > wav) { float2 h = sWA[w]; EWB = EWA*h.y + EWB; EWA = EWA*h.x; }

        float EA = __shfl_down(IA, 1, 64);
        float EB = __shfl_down(IB, 1, 64);
        if (lane == 63) { EA = 1.f; EB = 0.f; }

        float y = EA * EWB + EB;

        #pragma unroll
        for (int k = IPTC - 1; k >= 0; --k) {
            float ak = ((mask >> k) & 1u) ? 0.f : DISC;
            if (base + k >= T) ak = 1.f;
            y = ak * y + r[k]; r[k] = y;
        }
        #pragma unroll
        for (int k = 0; k < IPTC; ++k) {
            long long i = base + k;
            if (i < T) out[i] = r[k];
        }

        At = g.x; Bt = g.y; lt = cl;
    }

    if (t == 0) {
        agg[b] = make_float2(At, Bt);
        lastT[b] = max(lt, (int)lo - 1);   // lo-1 == "no terminal in block"
    }
}

// K2: per-block y_in from aggregates above, then sparse tail correction.
__global__ __launch_bounds__(FTPB) void k_fix(
        const float2* __restrict__ agg, const int* __restrict__ lastT,
        float* __restrict__ out, int numBlocks, long long T) {
    __shared__ float2 sWB[FTPB / 64];

    const int t = threadIdx.x;
    const int lane = t & 63, wav = t >> 6;
    const int b = blockIdx.x;

    const int cpt = (numBlocks + FTPB - 1) / FTPB;   // 8 for 2048
    float VA = 1.f, VB = 0.f;
    #pragma unroll
    for (int k = cpt - 1; k >= 0; --k) {             // descending g: inner first
        int g = t * cpt + k;
        if (g > b && g < numBlocks) {
            float2 q = agg[g];
            VB = q.x * VB + q.y; VA = q.x * VA;
        }
    }
    wave_suffix_scan(VA, VB, lane);
    if (lane == 0) sWB[wav] = make_float2(VA, VB);
    __syncthreads();

    float FA = sWB[0].x, FB = sWB[0].y;              // wave 0 outermost
    #pragma unroll
    for (int w = 1; w < FTPB / 64; ++w) {
        float2 h = sWB[w];
        FB = FA * h.y + FB; FA = FA * h.x;
    }
    const float yin = FB;                            // y entering block b (x=0)
    if (yin == 0.f) return;

    const long long lo = (long long)b * TILE;
    const long long hi = min(lo + (long long)TILE, T) - 1;
    const long long start = (long long)lastT[b] + 1; // >= lo by construction

    for (long long i = start + t; i <= hi; i += FTPB) {
        float d = (float)(int)(hi + 1 - i);
        out[i] += exp2f(d * L2DISC) * yin;
    }
}

extern "C" void kernel_launch(void* const* d_in, const int* in_sizes, int n_in,
                              void* d_out, int out_size, void* d_ws, size_t ws_size,
                              hipStream_t stream) {
    const int*   term = (const int*)d_in[0];
    const float* rew  = (const float*)d_in[1];
    float*       out  = (float*)d_out;

    const long long T = (long long)in_sizes[1];
    const int numBlocks = (int)((T + TILE - 1) / TILE);   // 2048 for T=2^24

    float2* agg   = (float2*)d_ws;
    int*    lastT = (int*)(agg + numBlocks);

    k_local<<<numBlocks, TPB, 0, stream>>>(term, rew, out, agg, lastT, T);
    k_fix  <<<numBlocks, FTPB, 0, stream>>>(agg, lastT, out, numBlocks, T);
}